// Round 8
// baseline (249.059 us; speedup 1.0000x reference)
//
#include <hip/hip_runtime.h>

// IntegerNeuron: T-step integrate-fire scan over [T,B,C,H,W].
// T=8, B=32, C=128, H=32, W=32. Memory-bound: 128 MiB in + 128 MiB out.
//
// Numerics: bit-exact vs fp32 reference (hard threshold). Reference order:
//   drive = x*tau; mem = (mem + drive) + bias_scaled;
//   spike = mem >= vth_scaled; mem -= spike*vth_scaled.
// tau==4.0 (pow2) => x*tau exact => FMA contraction bit-identical.
// jnp.round == rintf (half-to-even).
//
// History (per-dispatch):
//  base: compiler loop, plain stores ................ 84.7-85.5 us, 2.37 TB/s
//  R1  : nt-builtin stores .......................... 92 us (worse)
//  R3  : asm loads "=v" ............................. container fail (no early-clobber)
//  R4  : 8-deep asm load burst, plain stores ........ 89-92 us => MLP not limiter
//  R5  : depth-1 + asm `sc0 sc1 nt` stores .......... 79.4 us (BEST)
//  R6  : 3-deep counted vmcnt, never drain stores ... 88.6-89.6 us (worse)
//  R7  : phase-separated scan->store burst .......... container fail, no counters.
//        Only code delta vs proven R5 store form: missing "memory" clobber.
//        Infra telemetry (760-1000s npz pushes in R5/R6) suggests flake; this
//        round re-runs R7 with stores byte-exact to R5's working form.
//
// R8 theory (unchanged from R7): all interleaved-RW variants equilibrate at
// 2.3-2.5 TB/s while pure-write fillBuffer hits 6.7 TB/s in the same profile.
// The untested axis is stream phasing: run the whole 8-step scan holding the
// 8 spike f4s in registers (32 VGPR), then burst all 8 stores at the end.
// Waves run in near-lockstep => dispatch is read-dominant early, write-
// dominant late => minimal DRAM RW turnaround / channel contention. Side
// benefit: no store pending during the scan, so compiler vmcnt waits are
// load-only. Named sp0..sp7 (rule #20: no runtime-indexed arrays).

typedef float f4 __attribute__((ext_vector_type(4)));

constexpr int T_STEPS = 8;
constexpr int NB = 32, NC = 128, NH = 32, NW = 32;
constexpr int NSP = NB * NC * NH * NW;   // 4,194,304 spatial positions
constexpr int N4  = NSP / 4;             // 1,048,576 float4 positions
constexpr int HW4 = (NH * NW) / 4;       // 256 float4 per (b,c) plane == blockDim

__global__ __launch_bounds__(256) void IntegerNeuron_84842783965742_kernel(
    const f4*    __restrict__ x,            // [T, B, C, H, W] as float4
    const float* __restrict__ prev_scale,   // [C]
    const float* __restrict__ prev_bias,    // [C]
    const float* __restrict__ vth,          // scalar
    const int*   __restrict__ tau,          // scalar int
    const int*   __restrict__ is_first,     // scalar int
    f4*          __restrict__ out)          // [T, B, C, H, W] as float4
{
    const int i = blockIdx.x * blockDim.x + threadIdx.x;   // float4 index
    const int c = blockIdx.x % NC;  // uniform per block (blockDim == HW4)

    const float tau_f = (float)tau[0];
    const float denom = prev_scale[c] + 1e-12f;
    const float bs = rintf(prev_bias[c] * tau_f / denom);  // bias_scaled[c]
    const float vs = rintf(vth[0] * tau_f / denom);        // vth_scaled[c]
    const float mul = is_first[0] ? 1.0f : tau_f;          // drive multiplier

    float m0 = 0.0f, m1 = 0.0f, m2 = 0.0f, m3 = 0.0f;      // mem in VGPRs
    f4 sp0, sp1, sp2, sp3, sp4, sp5, sp6, sp7;             // spikes in regs

#define STEP(spk, t)                                                        \
    do {                                                                    \
        const f4 xv = x[(size_t)(t) * N4 + i];  /* compiler-scheduled */    \
        /* mem = (mem + x*tau) + bias_scaled — reference association */     \
        m0 = (m0 + xv.x * mul) + bs;                                        \
        m1 = (m1 + xv.y * mul) + bs;                                        \
        m2 = (m2 + xv.z * mul) + bs;                                        \
        m3 = (m3 + xv.w * mul) + bs;                                        \
        (spk).x = (m0 >= vs) ? 1.0f : 0.0f;                                 \
        (spk).y = (m1 >= vs) ? 1.0f : 0.0f;                                 \
        (spk).z = (m2 >= vs) ? 1.0f : 0.0f;                                 \
        (spk).w = (m3 >= vs) ? 1.0f : 0.0f;                                 \
        /* soft reset: spike and vs integer-valued, product exact */        \
        m0 -= (spk).x * vs;                                                 \
        m1 -= (spk).y * vs;                                                 \
        m2 -= (spk).z * vs;                                                 \
        m3 -= (spk).w * vs;                                                 \
    } while (0)

    STEP(sp0, 0);
    STEP(sp1, 1);
    STEP(sp2, 2);
    STEP(sp3, 3);
    STEP(sp4, 4);
    STEP(sp5, 5);
    STEP(sp6, 6);
    STEP(sp7, 7);
#undef STEP

    // --- Terminal write burst: 8 stores back-to-back, no loads pending. ---
    // Byte-exact R5 store form (sc0 sc1 nt + "memory" clobber). Slice stride
    // 16 MiB = 0x1000000; max offset 128 MiB - 16 < 2^27 (sign bit clear),
    // same 32-bit voffset form R4/R5/R6 executed without fault.
    const unsigned int b0 = (unsigned int)i * 16u;
#define STOREK(spk, t)                                                      \
    do {                                                                    \
        const unsigned int ob = b0 + ((unsigned int)(t) << 24);             \
        asm volatile(                                                       \
            "global_store_dwordx4 %[off], %[val], %[base] sc0 sc1 nt"       \
            :                                                               \
            : [off] "v"(ob), [val] "v"(spk), [base] "s"(out)                \
            : "memory");                                                    \
    } while (0)
    STOREK(sp0, 0);
    STOREK(sp1, 1);
    STOREK(sp2, 2);
    STOREK(sp3, 3);
    STOREK(sp4, 4);
    STOREK(sp5, 5);
    STOREK(sp6, 6);
    STOREK(sp7, 7);
#undef STOREK
}

extern "C" void kernel_launch(void* const* d_in, const int* in_sizes, int n_in,
                              void* d_out, int out_size, void* d_ws, size_t ws_size,
                              hipStream_t stream) {
    const f4*    x          = (const f4*)d_in[0];
    const float* prev_scale = (const float*)d_in[1];
    const float* prev_bias  = (const float*)d_in[2];
    const float* vth        = (const float*)d_in[3];
    const int*   tau        = (const int*)d_in[4];
    const int*   is_first   = (const int*)d_in[5];
    f4*          out        = (f4*)d_out;

    dim3 block(256);
    dim3 grid(N4 / 256);   // 4096 blocks
    IntegerNeuron_84842783965742_kernel<<<grid, block, 0, stream>>>(
        x, prev_scale, prev_bias, vth, tau, is_first, out);
}

// Round 9
// 239.440 us; speedup vs baseline: 1.0402x; 1.0402x over previous
//
#include <hip/hip_runtime.h>

// IntegerNeuron: T-step integrate-fire scan over [T,B,C,H,W].
// T=8, B=32, C=128, H=32, W=32. Memory-bound: 128 MiB in + 128 MiB out.
//
// Numerics: bit-exact vs fp32 reference (hard threshold). Reference order:
//   drive = x*tau; mem = (mem + drive) + bias_scaled;
//   spike = mem >= vth_scaled; mem -= spike*vth_scaled.
// tau==4.0 (pow2) => x*tau exact => FMA contraction bit-identical.
// jnp.round == rintf (half-to-even).
//
// Session history (per-dispatch):
//  base: compiler loop, plain stores ................ 84.7-85.5 us, 2.37 TB/s
//  R1  : nt-builtin stores .......................... 92 us (worse)
//  R4  : 8-deep asm load burst, plain stores ........ 89-92 us
//  R5  : depth-1 + asm `sc0 sc1 nt` stores .......... 79.4 us (BEST; this file)
//  R6  : 3-deep counted vmcnt, never drain stores ... 88.6-89.6 us
//  R8  : per-wave phase-separated scan->store burst . 88.7-91.4 us
//
// Final model (fits all rounds): reads are outstanding-miss-tracking (MSHR)
// limited, not supply limited. Writes are posted — pure-write fillBuffer hits
// 6.7 TB/s at 9.5% occupancy in the same profile. Reads hold a line-fill
// entry per 128B line for the full ~900cy HBM/MALL latency; at ~32-64
// trackable lines/CU the chip-wide read ceiling is ~2.3-2.8 TB/s regardless
// of request supply — which is why depth 1/3/8, store policy, counted waits,
// and stream phasing ALL equilibrate at 2.3-2.5 TB/s. Traffic is compulsory
// (every byte read once, written once); no software lever changes MSHR count
// or miss latency. 128 MiB reads @ ~2.3 TB/s ~= 58 us + partially-overlapped
// posted writes ~= the measured 79 us.
//
// This file is the byte-exact R5 winner: compiler-scheduled depth-1 loop
// (compiler's own vmcnt scheduling proved fastest) + `sc0 sc1 nt` stores
// (-7% vs plain stores; mechanism is cheaper write-path policy, not L3
// residency — FETCH unchanged).

typedef float f4 __attribute__((ext_vector_type(4)));

constexpr int T_STEPS = 8;
constexpr int NB = 32, NC = 128, NH = 32, NW = 32;
constexpr int NSP = NB * NC * NH * NW;   // 4,194,304 spatial positions
constexpr int N4  = NSP / 4;             // 1,048,576 float4 positions
constexpr int HW4 = (NH * NW) / 4;       // 256 float4 per (b,c) plane == blockDim

__global__ __launch_bounds__(256) void IntegerNeuron_84842783965742_kernel(
    const f4*    __restrict__ x,            // [T, B, C, H, W] as float4
    const float* __restrict__ prev_scale,   // [C]
    const float* __restrict__ prev_bias,    // [C]
    const float* __restrict__ vth,          // scalar
    const int*   __restrict__ tau,          // scalar int
    const int*   __restrict__ is_first,     // scalar int
    f4*          __restrict__ out)          // [T, B, C, H, W] as float4
{
    const int i = blockIdx.x * blockDim.x + threadIdx.x;   // float4 index
    const int c = blockIdx.x % NC;  // uniform per block: blockDim == HW4, so
                                    // each block is exactly one (b,c) plane.

    const float tau_f = (float)tau[0];
    const float denom = prev_scale[c] + 1e-12f;
    const float bs = rintf(prev_bias[c] * tau_f / denom);  // bias_scaled[c]
    const float vs = rintf(vth[0] * tau_f / denom);        // vth_scaled[c]
    const float mul = is_first[0] ? 1.0f : tau_f;          // drive multiplier

    const unsigned int b0 = (unsigned int)i * 16u;         // byte offset, slice 0

    float m0 = 0.0f, m1 = 0.0f, m2 = 0.0f, m3 = 0.0f;      // mem in VGPRs

    #pragma unroll
    for (int t = 0; t < T_STEPS; ++t) {
        const f4 xv = x[(size_t)t * N4 + i];   // compiler-scheduled load

        // mem = (mem + x*tau) + bias_scaled  — matches reference association.
        m0 = (m0 + xv.x * mul) + bs;
        m1 = (m1 + xv.y * mul) + bs;
        m2 = (m2 + xv.z * mul) + bs;
        m3 = (m3 + xv.w * mul) + bs;

        f4 sp;
        sp.x = (m0 >= vs) ? 1.0f : 0.0f;
        sp.y = (m1 >= vs) ? 1.0f : 0.0f;
        sp.z = (m2 >= vs) ? 1.0f : 0.0f;
        sp.w = (m3 >= vs) ? 1.0f : 0.0f;

        // soft reset: spike and vs are integer-valued, product exact.
        m0 -= sp.x * vs;
        m1 -= sp.y * vs;
        m2 -= sp.z * vs;
        m3 -= sp.w * vs;

        // R5-winning store: no-allocate / system-scope policy bits.
        // Slice stride 16 MiB = 0x1000000; max offset < 2^27 (sign bit clear).
        const unsigned int ob = b0 + ((unsigned int)t << 24);
        asm volatile(
            "global_store_dwordx4 %[off], %[val], %[base] sc0 sc1 nt"
            :
            : [off] "v"(ob), [val] "v"(sp), [base] "s"(out)
            : "memory");
    }
}

extern "C" void kernel_launch(void* const* d_in, const int* in_sizes, int n_in,
                              void* d_out, int out_size, void* d_ws, size_t ws_size,
                              hipStream_t stream) {
    const f4*    x          = (const f4*)d_in[0];
    const float* prev_scale = (const float*)d_in[1];
    const float* prev_bias  = (const float*)d_in[2];
    const float* vth        = (const float*)d_in[3];
    const int*   tau        = (const int*)d_in[4];
    const int*   is_first   = (const int*)d_in[5];
    f4*          out        = (f4*)d_out;

    dim3 block(256);
    dim3 grid(N4 / 256);   // 4096 blocks
    IntegerNeuron_84842783965742_kernel<<<grid, block, 0, stream>>>(
        x, prev_scale, prev_bias, vth, tau, is_first, out);
}